// Round 15
// baseline (915.547 us; speedup 1.0000x reference)
//
#include <hip/hip_runtime.h>
#include <hip/hip_bf16.h>

// Ternary-quantized linear: out[M,N] = x[M,K] . W^T,  W[n,k] = q[n,k]*scale[n].
// R15: m201-style 8-wave port. 512 threads, block tile 256x256, 8 waves (2Mx4N),
//      wave tile 128x64 (acc[8][4], geometry byte-identical to R7/R14). Ring-3
//      LDS (A 3x32KB + B 3x4KB + 4KB dummy = 112KB, 1 block/CU). 4 phases/kt:
//      {DSA [+DSB] [+STAGE kt+2 @ph0]; bar; lgkm0; prio1; [unpack]; 16 MFMA;
//      prio0; bar}; counted vmcnt(5) at ph3 (10 loads in flight, waits oldest 5).
//      Coherent 2-waves/SIMD phase interleave = m201's 62%-MfmaUtil mechanism.
//      Pre-pass (x->bf16, W tight-pack) unchanged. Fallback = R5 fused.

#define M_DIM 8192
#define N_DIM 11008
#define K_DIM 4096
#define BM 256
#define BN 256
#define BK 64
#define KT 64
#define NB_N 43
#define NWG 1376                    // 32*43, %8 == 0

#define XBF_BYTES ((size_t)M_DIM * K_DIM * 2)        // 67108864
#define BT_BYTES  ((size_t)N_DIM * K_DIM / 4)        // 11272192
#define WS_NEED   (XBF_BYTES + BT_BYTES)             // 78381056

typedef __attribute__((ext_vector_type(8))) short bf16x8;
typedef __attribute__((ext_vector_type(4))) float f32x4;

__device__ inline unsigned int bf16b(float f) {
  union { __hip_bfloat16 h; unsigned short u; } cv;
  cv.h = __float2bfloat16(f);
  return (unsigned int)cv.u;
}

__device__ __forceinline__ void gload_lds16(const void* g, void* l) {
  __builtin_amdgcn_global_load_lds(
      (const __attribute__((address_space(1))) unsigned int*)g,
      (__attribute__((address_space(3))) unsigned int*)l, 16, 0, 0);
}

// ---------------- pre-pass: x fp32->bf16 ; PW one-byte-per-int32 -> tight bytes
#define XCVT_BLOCKS 16384   // 16384*256*8 = 33554432 floats
#define PACK_BLOCKS 5504    // 5504*256*8  = 11272192 int32s
__global__ __launch_bounds__(256)
void xcvt_kernel(const float* __restrict__ X, unsigned short* __restrict__ Xbf) {
  const size_t i8 = ((size_t)blockIdx.x * 256 + threadIdx.x) * 8;
  float4 a = *(const float4*)(X + i8);
  float4 c = *(const float4*)(X + i8 + 4);
  uint4 o;
  o.x = bf16b(a.x) | (bf16b(a.y) << 16);
  o.y = bf16b(a.z) | (bf16b(a.w) << 16);
  o.z = bf16b(c.x) | (bf16b(c.y) << 16);
  o.w = bf16b(c.z) | (bf16b(c.w) << 16);
  *(uint4*)(Xbf + i8) = o;
}

__global__ __launch_bounds__(256)
void btight_kernel(const int* __restrict__ PW, unsigned char* __restrict__ Bt) {
  const size_t i8 = ((size_t)blockIdx.x * 256 + threadIdx.x) * 8;
  int4 p = *(const int4*)(PW + i8);
  int4 q = *(const int4*)(PW + i8 + 4);
  uint2 o;
  o.x = (unsigned)(p.x & 255) | ((unsigned)(p.y & 255) << 8) |
        ((unsigned)(p.z & 255) << 16) | ((unsigned)(p.w & 255) << 24);
  o.y = (unsigned)(q.x & 255) | ((unsigned)(q.y & 255) << 8) |
        ((unsigned)(q.z & 255) << 16) | ((unsigned)(q.w & 255) << 24);
  *(uint2*)(Bt + i8) = o;
}

// ---------------- main: 256x256 block, 8 waves of 128x64, ring-3, 4 phases/kt
__global__ __launch_bounds__(512, 2)
void qlin_w8_kernel(const unsigned short* __restrict__ Xbf,
                    const unsigned char* __restrict__ Bt,
                    const float* __restrict__ SC, float* __restrict__ OUT) {
  __shared__ unsigned short As[3][BM * BK];   // 3 x 32 KB ring
  __shared__ unsigned char  Bs[3][BN * 16];   // 3 x 4 KB ring, packed
  __shared__ unsigned char  Bdummy[4 * 1024]; // waves 4-7 staging sink

  const int tid = threadIdx.x;
  const int lane = tid & 63;
  const int w = tid >> 6;        // 0..7
  const int wm = w >> 2;         // 0..1 (M half: 128 rows)
  const int wn = w & 3;          // 0..3 (N quarter: 64 cols)

  const int wg = blockIdx.x;
  const int swz = (wg & 7) * (NWG / 8) + (wg >> 3);
  const int bm = swz / NB_N;
  const int bn = swz - bm * NB_N;

  // A stage map (R7-verified, wave region = rows w*32..w*32+31):
  // LDS byte o = w*4096 + i*1024 + lane*16 -> row = w*32+i*8+(lane>>3),
  // slot = lane&7; source chunk = slot ^ (row&7) = (lane&7)^(lane>>3).
  const int l3 = lane >> 3;
  const char* ab0 = (const char*)Xbf +
      (size_t)(bm * BM + w * 32 + l3) * (K_DIM * 2) + ((lane & 7) ^ l3) * 16;
  // B stage: waves 0-3 real rows (w*64+lane); waves 4-7 duplicate -> dummy.
  const char* bb = (const char*)Bt +
      (size_t)(bn * BN + (w & 3) * 64 + lane) * (K_DIM / 4);
  unsigned char* bdst[3];
  if (w < 4) { bdst[0] = &Bs[0][w * 1024]; bdst[1] = &Bs[1][w * 1024]; bdst[2] = &Bs[2][w * 1024]; }
  else       { bdst[0] = bdst[1] = bdst[2] = &Bdummy[(w - 4) * 1024]; }

#define STAGE(IDX, KT_) do {                                           \
    unsigned short* ad_ = &As[IDX][w * 2048];                          \
    gload_lds16(ab0 + (KT_)*128,           ad_);                       \
    gload_lds16(ab0 + (KT_)*128 + 65536,   ad_ + 512);                 \
    gload_lds16(ab0 + (KT_)*128 + 131072,  ad_ + 1024);                \
    gload_lds16(ab0 + (KT_)*128 + 196608,  ad_ + 1536);                \
    gload_lds16(bb  + (KT_)*16,            bdst[IDX]);                 \
  } while (0)

  f32x4 acc[8][4];
#pragma unroll
  for (int i = 0; i < 8; ++i)
#pragma unroll
    for (int j = 0; j < 4; ++j) acc[i][j] = (f32x4){0.f, 0.f, 0.f, 0.f};

  // fragment geometry (R7, re-based by wm/wn)
  const int l4 = lane >> 4;
  const int axor = lane & 7;
  const int arowb = (wm * 128 + (lane & 15)) * 128;   // + (H*4+m)*2048 + chunk
  const int hb = l4 >> 1;
  const unsigned hoff = (unsigned)(l4 & 1) * 16;
  const int rbase = (wn * 64 + (lane & 15)) * 16 + hb * 4;

  bf16x8 af[4];
  bf16x8 bfr[4];
  unsigned d4[4];

#define DSA(CB, KK, H) do {                                                    \
    const char* asb_ = (const char*)&As[CB][0];                                \
    _Pragma("unroll")                                                          \
    for (int m = 0; m < 4; ++m)                                                \
      af[m] = *(const bf16x8*)(asb_ + arowb + ((H) * 4 + m) * 2048 +           \
                               ((((KK) * 4 + l4) ^ axor) << 4));               \
  } while (0)

#define DSB(CB, KK) do {                                                       \
    const unsigned char* bsb_ = &Bs[CB][0];                                    \
    _Pragma("unroll")                                                          \
    for (int n = 0; n < 4; ++n)                                                \
      d4[n] = *(const unsigned*)(bsb_ + rbase + n * 256 + (KK) * 8);           \
  } while (0)

#define UNPACK() do {                                                          \
    _Pragma("unroll")                                                          \
    for (int n = 0; n < 4; ++n) {                                              \
      const unsigned w16 = (d4[n] >> hoff) & 0xFFFFu;                          \
      const unsigned u = w16 | (w16 << 14);                                    \
      union { uint4 s; bf16x8 v; } t;                                          \
      t.s.x = ((u << 14) & 0xC000C000u) + 0x40004000u;                         \
      t.s.y = ((u << 10) & 0xC000C000u) + 0x40004000u;                         \
      t.s.z = ((u << 6)  & 0xC000C000u) + 0x40004000u;                         \
      t.s.w = ((u << 2)  & 0xC000C000u) + 0x40004000u;                         \
      bfr[n] = t.v;                                                            \
    }                                                                          \
  } while (0)

#define MFMA16(H) do {                                                         \
    _Pragma("unroll")                                                          \
    for (int m = 0; m < 4; ++m)                                                \
      _Pragma("unroll")                                                        \
      for (int n = 0; n < 4; ++n)                                              \
        acc[(H) * 4 + m][n] = __builtin_amdgcn_mfma_f32_16x16x32_bf16(         \
            af[m], bfr[n], acc[(H) * 4 + m][n], 0, 0, 0);                      \
  } while (0)

#define BAR() __builtin_amdgcn_s_barrier()
#define LGKM0() asm volatile("s_waitcnt lgkmcnt(0)" ::: "memory")
#define PRIO(P) __builtin_amdgcn_s_setprio(P)

  // prologue: buffers 0 and 1 in flight; retire buffer 0's 5 (counted)
  STAGE(0, 0);
  STAGE(1, 1);
  asm volatile("s_waitcnt vmcnt(5)" ::: "memory");
  BAR();

  int cb = 0, sb = 2;   // current buffer, stage buffer (kt+2)
  for (int kt = 0; kt < KT; ++kt) {
    // ---- phase 0: (kk=0, m-half 0) + stage kt+2 ----
    DSA(cb, 0, 0);
    DSB(cb, 0);
    if (kt + 2 < KT) STAGE(sb, kt + 2);
    BAR(); LGKM0(); PRIO(1);
    UNPACK();
    MFMA16(0);
    PRIO(0); BAR();
    // ---- phase 1: (kk=0, m-half 1) ----
    DSA(cb, 0, 1);
    BAR(); LGKM0(); PRIO(1);
    MFMA16(1);
    PRIO(0); BAR();
    // ---- phase 2: (kk=1, m-half 0) ----
    DSA(cb, 1, 0);
    DSB(cb, 1);
    BAR(); LGKM0(); PRIO(1);
    UNPACK();
    MFMA16(0);
    PRIO(0); BAR();
    // ---- phase 3: (kk=1, m-half 1) + counted vmcnt for kt+1's buffer ----
    DSA(cb, 1, 1);
    if (kt < KT - 2) { asm volatile("s_waitcnt vmcnt(5)" ::: "memory"); }
    else             { asm volatile("s_waitcnt vmcnt(0)" ::: "memory"); }
    BAR(); LGKM0(); PRIO(1);
    MFMA16(1);
    PRIO(0); BAR();
    cb = (cb == 2) ? 0 : cb + 1;
    sb = (sb == 2) ? 0 : sb + 1;
  }
#undef STAGE
#undef DSA
#undef DSB
#undef UNPACK
#undef MFMA16

  // epilogue: acc * (-0.5*scale[col]); C/D: col=lane&15, row=(lane>>4)*4+r
  const int gc0 = bn * BN + wn * 64 + (lane & 15);
  const int gr0 = bm * BM + wm * 128 + (l4 << 2);
  float sc[4];
#pragma unroll
  for (int n = 0; n < 4; ++n) sc[n] = -0.5f * SC[gc0 + n * 16];
#pragma unroll
  for (int m = 0; m < 8; ++m)
#pragma unroll
    for (int n = 0; n < 4; ++n)
#pragma unroll
      for (int r = 0; r < 4; ++r)
        OUT[(size_t)(gr0 + m * 16 + r) * N_DIM + gc0 + n * 16] = acc[m][n][r] * sc[n];
}

// ---------------- fallback: R5 fused kernel (ws too small) ----------
#define FB_NWG 2752
#define BSTRIDE 20
__global__ __launch_bounds__(256, 2)
void qlin_fused_kernel(const float* __restrict__ X, const int* __restrict__ PW,
                       const float* __restrict__ SC, float* __restrict__ OUT) {
  __shared__ unsigned short Asf[128 * 64];
  __shared__ unsigned char Bp[256 * BSTRIDE];

  const int tid = threadIdx.x;
  const int wg = blockIdx.x;
  const int swz = (wg & 7) * (FB_NWG / 8) + (wg >> 3);
  const int bm = swz / 43;
  const int bn = swz - bm * 43;

  const int lane = tid & 63;
  const int wave = tid >> 6;
  const int wr = wave >> 1;
  const int wc = wave & 1;

  const int arow = tid >> 3;
  const int ac8  = tid & 7;
  const float* xptr = X + (size_t)(bm * 128 + arow) * K_DIM + ac8 * 8;
  const unsigned int aswz = ((unsigned)arow & 7u) << 4;

  const int bc  = tid & 3;
  const int br0 = tid >> 2;
  const int* pwptr = PW + (size_t)(bn * 256 + br0) * (K_DIM / 4) + bc * 4;
  const int bwoff = (bc & 1) * 8 + (bc >> 1) * 2;

  f32x4 acc[4][8];
#pragma unroll
  for (int i = 0; i < 4; ++i)
#pragma unroll
    for (int j = 0; j < 8; ++j) acc[i][j] = (f32x4){0.f, 0.f, 0.f, 0.f};

  float4 av[4][2];
  int4 bv[4];
#pragma unroll
  for (int j = 0; j < 4; ++j) {
    av[j][0] = *(const float4*)(xptr + (size_t)(32 * j) * K_DIM);
    av[j][1] = *(const float4*)(xptr + (size_t)(32 * j) * K_DIM + 4);
  }
#pragma unroll
  for (int j = 0; j < 4; ++j)
    bv[j] = *(const int4*)(pwptr + (size_t)(64 * j) * (K_DIM / 4));

  for (int kt = 0; kt < 64; ++kt) {
    __syncthreads();
#pragma unroll
    for (int j = 0; j < 4; ++j) {
      uint4 wv;
      wv.x = bf16b(av[j][0].x) | (bf16b(av[j][0].y) << 16);
      wv.y = bf16b(av[j][0].z) | (bf16b(av[j][0].w) << 16);
      wv.z = bf16b(av[j][1].x) | (bf16b(av[j][1].y) << 16);
      wv.w = bf16b(av[j][1].z) | (bf16b(av[j][1].w) << 16);
      *(uint4*)((char*)Asf + (arow + 32 * j) * 128 + (((unsigned)ac8 * 16u) ^ aswz)) = wv;
    }
#pragma unroll
    for (int j = 0; j < 4; ++j) {
      const unsigned int ulo = ((unsigned)bv[j].x & 255u) | (((unsigned)bv[j].y & 255u) << 8);
      const unsigned int uhi = ((unsigned)bv[j].z & 255u) | (((unsigned)bv[j].w & 255u) << 8);
      unsigned char* dst = Bp + (br0 + 64 * j) * BSTRIDE + bwoff;
      *(unsigned short*)(dst)     = (unsigned short)ulo;
      *(unsigned short*)(dst + 4) = (unsigned short)uhi;
    }
    __syncthreads();

    if (kt + 1 < 64) {
#pragma unroll
      for (int j = 0; j < 4; ++j) {
        av[j][0] = *(const float4*)(xptr + (kt + 1) * 64 + (size_t)(32 * j) * K_DIM);
        av[j][1] = *(const float4*)(xptr + (kt + 1) * 64 + (size_t)(32 * j) * K_DIM + 4);
      }
#pragma unroll
      for (int j = 0; j < 4; ++j)
        bv[j] = *(const int4*)(pwptr + (kt + 1) * 16 + (size_t)(64 * j) * (K_DIM / 4));
    }

    const int bh = lane >> 4;
    const int bcol0 = wc * 128 + (lane & 15);
    unsigned int d[8];
#pragma unroll
    for (int n = 0; n < 8; ++n)
      d[n] = *(const unsigned int*)(Bp + (bcol0 + n * 16) * BSTRIDE + bh * 4);

    const unsigned int rswz = ((unsigned)lane & 7u) << 4;
#pragma unroll
    for (int kk = 0; kk < 2; ++kk) {
      bf16x8 af[4];
      const unsigned int coff = (((unsigned)(kk * 4 + (lane >> 4))) * 16u) ^ rswz;
#pragma unroll
      for (int m = 0; m < 4; ++m)
        af[m] = *(const bf16x8*)((const char*)Asf + (wr * 64 + m * 16 + (lane & 15)) * 128 + coff);
#pragma unroll
      for (int n = 0; n < 8; ++n) {
        const unsigned int w16 = kk ? (d[n] >> 16) : (d[n] & 0xFFFFu);
        const unsigned int u = w16 | (w16 << 14);
        union { uint4 s; bf16x8 v; } bfr;
        bfr.s.x = ((u << 14) & 0xC000C000u) + 0x40004000u;
        bfr.s.y = ((u << 10) & 0xC000C000u) + 0x40004000u;
        bfr.s.z = ((u << 6)  & 0xC000C000u) + 0x40004000u;
        bfr.s.w = ((u << 2)  & 0xC000C000u) + 0x40004000u;
#pragma unroll
        for (int m = 0; m < 4; ++m)
          acc[m][n] = __builtin_amdgcn_mfma_f32_16x16x32_bf16(af[m], bfr.v, acc[m][n], 0, 0, 0);
      }
    }
  }

  const int gc0 = bn * 256 + wc * 128 + (lane & 15);
  const int gr0 = bm * 128 + wr * 64 + ((lane >> 4) << 2);
  float sc[8];
#pragma unroll
  for (int n = 0; n < 8; ++n) sc[n] = -0.5f * SC[gc0 + n * 16];
#pragma unroll
  for (int m = 0; m < 4; ++m)
#pragma unroll
    for (int n = 0; n < 8; ++n)
#pragma unroll
      for (int r = 0; r < 4; ++r)
        OUT[(size_t)(gr0 + m * 16 + r) * N_DIM + gc0 + n * 16] = acc[m][n][r] * sc[n];
}

extern "C" void kernel_launch(void* const* d_in, const int* in_sizes, int n_in,
                              void* d_out, int out_size, void* d_ws, size_t ws_size,
                              hipStream_t stream) {
  const float* x  = (const float*)d_in[0];
  const int*   pw = (const int*)d_in[1];
  const float* sc = (const float*)d_in[2];
  float* out = (float*)d_out;
  (void)in_sizes; (void)n_in; (void)out_size;

  if (ws_size >= WS_NEED) {
    unsigned short* xbf = (unsigned short*)d_ws;
    unsigned char* bt = (unsigned char*)d_ws + XBF_BYTES;
    xcvt_kernel<<<dim3(XCVT_BLOCKS), dim3(256), 0, stream>>>(x, xbf);
    btight_kernel<<<dim3(PACK_BLOCKS), dim3(256), 0, stream>>>(pw, bt);
    qlin_w8_kernel<<<dim3(NWG), dim3(512), 0, stream>>>(xbf, bt, sc, out);
  } else {
    qlin_fused_kernel<<<dim3(FB_NWG), dim3(256), 0, stream>>>(x, pw, sc, out);
  }
}

// Round 16
// 630.121 us; speedup vs baseline: 1.4530x; 1.4530x over previous
//
#include <hip/hip_runtime.h>
#include <hip/hip_bf16.h>

// Ternary-quantized linear: out[M,N] = x[M,K] . W^T,  W[n,k] = q[n,k]*scale[n].
// R16: R14 structure (best measured: 128x256 block, 4 waves of 128x64, BK=128
//      dbuf, counted vmcnt(10), 2 raw barriers/kt) with 32x32x16 MFMA
//      (ceiling 2495 vs 2176 TF; half the MFMA instrs -> issue headroom for
//      SWAR unpack). A image/stage identical to R14. B image k-major
//      [kt][ks][256 rows][4B] (bank = row mod 32, conflict-free; one 16-bit
//      SWAR unpack = one whole B fragment). A frag: row=lane&31,
//      k=(lane>>5)*8+e (contiguous-8 pattern verified by R1's 16x16x32).
//      C/D (m74/m101): col=lane&31, row=(reg&3)+8*(reg>>2)+4*(lane>>5).

#define M_DIM 8192
#define N_DIM 11008
#define K_DIM 4096
#define BM 128
#define BN 256
#define KT32 32                     // K-tiles of 128
#define NB_N 43
#define NWG 2752                    // 64*43, %8 == 0

#define XBF_BYTES ((size_t)M_DIM * K_DIM * 2)        // 67108864
#define BT_BYTES  ((size_t)N_DIM * K_DIM / 4)        // 11272192
#define WS_NEED   (XBF_BYTES + BT_BYTES)             // 78381056

typedef __attribute__((ext_vector_type(8))) short bf16x8;
typedef __attribute__((ext_vector_type(4))) float f32x4;
typedef __attribute__((ext_vector_type(16))) float f32x16;

__device__ inline unsigned int bf16b(float f) {
  union { __hip_bfloat16 h; unsigned short u; } cv;
  cv.h = __float2bfloat16(f);
  return (unsigned int)cv.u;
}

__device__ __forceinline__ void gload_lds16(const void* g, void* l) {
  __builtin_amdgcn_global_load_lds(
      (const __attribute__((address_space(1))) unsigned int*)g,
      (__attribute__((address_space(3))) unsigned int*)l, 16, 0, 0);
}

// ---------------- pre-pass: x fp32->bf16 ----------------
#define XCVT_BLOCKS 16384   // 16384*256*8 = 33554432 floats
__global__ __launch_bounds__(256)
void xcvt_kernel(const float* __restrict__ X, unsigned short* __restrict__ Xbf) {
  const size_t i8 = ((size_t)blockIdx.x * 256 + threadIdx.x) * 8;
  float4 a = *(const float4*)(X + i8);
  float4 c = *(const float4*)(X + i8 + 4);
  uint4 o;
  o.x = bf16b(a.x) | (bf16b(a.y) << 16);
  o.y = bf16b(a.z) | (bf16b(a.w) << 16);
  o.z = bf16b(c.x) | (bf16b(c.y) << 16);
  o.w = bf16b(c.z) | (bf16b(c.w) << 16);
  *(uint4*)(Xbf + i8) = o;
}

// ---------------- pre-pass: B k-major packed image ----------------
// Output dword [bn][kt][ks][row]: weights k = kt*128+ks*16 .. +15 of W-row
// n = bn*256+row, 2 bits each at bit 2*(k - kt*128 - ks*16).
#define BRE_BLOCKS 1376     // 1376*256 = 352256 = 43*32*256 (bn,kt,row)
__global__ __launch_bounds__(256)
void breorder_kernel(const int* __restrict__ PW, unsigned char* __restrict__ Bt) {
  const int ti = blockIdx.x * 256 + threadIdx.x;
  const int row = ti & 255;
  const int kt  = (ti >> 8) & 31;
  const int bn  = ti >> 13;
  const int* src = PW + (size_t)(bn * 256 + row) * (K_DIM / 4) + kt * 32;
  unsigned* dst = (unsigned*)Bt + (size_t)bn * 65536 + kt * 2048 + row;
#pragma unroll
  for (int ks = 0; ks < 8; ++ks) {
    int4 v = *(const int4*)(src + ks * 4);
    dst[ks * 256] = ((unsigned)v.x & 255u) | (((unsigned)v.y & 255u) << 8) |
                    (((unsigned)v.z & 255u) << 16) | (((unsigned)v.w & 255u) << 24);
  }
}

// ---------------- main: 128x256 block, 4 waves of 128x64, BK=128 dbuf, 32x32 MFMA
__global__ __launch_bounds__(256, 2)
void qlin_mm32_kernel(const unsigned short* __restrict__ Xbf,
                      const unsigned char* __restrict__ Bt,
                      const float* __restrict__ SC, float* __restrict__ OUT) {
  __shared__ unsigned short As[2][2][8192];  // [buf][khalf][128 x 64 bf16] = 64 KB
  __shared__ unsigned char  Bs[2][8192];     // [buf][k-major packed image] = 16 KB

  const int tid = threadIdx.x;
  const int lane = tid & 63;
  const int w = tid >> 6;

  const int wg = blockIdx.x;
  const int swz = (wg & 7) * (NWG / 8) + (wg >> 3);
  const int bm = swz / NB_N;
  const int bn = swz - bm * NB_N;

  // A stage map (R7/R14-verified): per khalf 4 gload_lds/thread.
  // LDS byte o = w*4096 + i*1024 + lane*16 -> row = w*32+i*8+(lane>>3),
  // slot = lane&7; source chunk = slot ^ (row&7) = (lane&7)^(lane>>3).
  const int l3 = lane >> 3;
  const char* ab0 = (const char*)Xbf +
      (size_t)(bm * BM + w * 32 + l3) * (K_DIM * 2) + ((lane & 7) ^ l3) * 16;
  // B stage: linear copy of k-major image, wave w covers bytes w*2048..+2047.
  const char* bimg = (const char*)Bt + (size_t)(bn * KT32) * 8192;

  // 10 loads per STAGE (8 A + 2 B)
#define STAGE(IDX, KT_) do {                                                   \
    _Pragma("unroll")                                                          \
    for (int h = 0; h < 2; ++h) {                                              \
      unsigned short* ad_ = &As[IDX][h][w * 2048];                             \
      const char* as_ = ab0 + (KT_) * 256 + h * 128;                           \
      gload_lds16(as_,           ad_);                                         \
      gload_lds16(as_ + 65536,   ad_ + 512);                                   \
      gload_lds16(as_ + 131072,  ad_ + 1024);                                  \
      gload_lds16(as_ + 196608,  ad_ + 1536);                                  \
    }                                                                          \
    const char* bs_ = bimg + (size_t)(KT_) * 8192 + w * 2048 + lane * 16;      \
    unsigned char* bd_ = &Bs[IDX][w * 2048];                                   \
    gload_lds16(bs_,          bd_);                                            \
    gload_lds16(bs_ + 1024,   bd_ + 1024);                                     \
  } while (0)

  f32x16 acc[4][2];
#pragma unroll
  for (int i = 0; i < 4; ++i)
#pragma unroll
    for (int j = 0; j < 2; ++j)
#pragma unroll
      for (int r = 0; r < 16; ++r) acc[i][j][r] = 0.f;

  // fragment geometry (32x32x16): A row = lane&31, k = (lane>>5)*8 + e.
  const int l31 = lane & 31;
  const int l5 = lane >> 5;
  const int a7 = lane & 7;            // row&7 for A rows (32 | row-base)
  const unsigned hoff = (unsigned)l5 * 16;
  const int arow32 = l31 * 128;       // A row byte offset within khalf image

#define COMPUTE(B_) do {                                                        \
    _Pragma("unroll")                                                           \
    for (int ks = 0; ks < 8; ++ks) {                                            \
      const int kh_ = ks >> 2;                                                  \
      const int kl_ = ks & 3;                                                   \
      const char* asb_ = (const char*)&As[B_][kh_][0];                          \
      const unsigned char* bsb_ = &Bs[B_][0];                                   \
      bf16x8 af[4];                                                             \
      _Pragma("unroll")                                                         \
      for (int mt = 0; mt < 4; ++mt)                                            \
        af[mt] = *(const bf16x8*)(asb_ + mt * 4096 + arow32 +                   \
                                  (((kl_ * 2 + l5) ^ a7) << 4));                \
      bf16x8 bfr[2];                                                            \
      _Pragma("unroll")                                                         \
      for (int nt = 0; nt < 2; ++nt) {                                          \
        const unsigned d = *(const unsigned*)(bsb_ + ks * 1024 +                \
                                              (w * 64 + nt * 32 + l31) * 4);    \
        const unsigned w16 = (d >> hoff) & 0xFFFFu;                             \
        const unsigned u = w16 | (w16 << 14);                                   \
        union { uint4 s; bf16x8 v; } t;                                         \
        t.s.x = ((u << 14) & 0xC000C000u) + 0x40004000u;                        \
        t.s.y = ((u << 10) & 0xC000C000u) + 0x40004000u;                        \
        t.s.z = ((u << 6)  & 0xC000C000u) + 0x40004000u;                        \
        t.s.w = ((u << 2)  & 0xC000C000u) + 0x40004000u;                        \
        bfr[nt] = t.v;                                                          \
      }                                                                         \
      _Pragma("unroll")                                                         \
      for (int mt = 0; mt < 4; ++mt)                                            \
        _Pragma("unroll")                                                       \
        for (int nt = 0; nt < 2; ++nt)                                          \
          acc[mt][nt] = __builtin_amdgcn_mfma_f32_32x32x16_bf16(                \
              af[mt], bfr[nt], acc[mt][nt], 0, 0, 0);                           \
    }                                                                           \
  } while (0)

  // ---- main loop: dbuf, counted vmcnt(10), 2 raw barriers per kt ----
  STAGE(0, 0);                                   // 10 loads in flight
  int cur = 0;
  for (int kt = 0; kt < KT32 - 1; ++kt) {
    STAGE(cur ^ 1, kt + 1);                      // 20 in flight
    asm volatile("s_waitcnt vmcnt(10)" ::: "memory");  // cur's 10 done; nxt's fly
    __builtin_amdgcn_s_barrier();                // all waves: cur ready
    COMPUTE(cur);
    asm volatile("s_waitcnt lgkmcnt(0)" ::: "memory"); // my reads of cur done
    __builtin_amdgcn_s_barrier();                // all waves done reading cur
    cur ^= 1;
  }
  asm volatile("s_waitcnt vmcnt(0)" ::: "memory");     // tail: last buffer
  __builtin_amdgcn_s_barrier();
  COMPUTE(cur);
#undef STAGE
#undef COMPUTE

  // epilogue: acc * (-0.5*scale[col]); C/D (m74/m101):
  // col = lane&31, row = (reg&3) + 8*(reg>>2) + 4*(lane>>5)
#pragma unroll
  for (int nt = 0; nt < 2; ++nt) {
    const int gc = bn * BN + w * 64 + nt * 32 + l31;
    const float s = -0.5f * SC[gc];
#pragma unroll
    for (int mt = 0; mt < 4; ++mt) {
      const int gr0 = bm * BM + mt * 32 + 4 * l5;
#pragma unroll
      for (int reg = 0; reg < 16; ++reg) {
        const int row = gr0 + (reg & 3) + 8 * (reg >> 2);
        OUT[(size_t)row * N_DIM + gc] = acc[mt][nt][reg] * s;
      }
    }
  }
}

// ---------------- fallback: R5 fused kernel (ws too small) ----------
#define BSTRIDE 20
__global__ __launch_bounds__(256, 2)
void qlin_fused_kernel(const float* __restrict__ X, const int* __restrict__ PW,
                       const float* __restrict__ SC, float* __restrict__ OUT) {
  __shared__ unsigned short Asf[128 * 64];
  __shared__ unsigned char Bp[256 * BSTRIDE];

  const int tid = threadIdx.x;
  const int wg = blockIdx.x;
  const int swz = (wg & 7) * (NWG / 8) + (wg >> 3);
  const int bm = swz / NB_N;
  const int bn = swz - bm * NB_N;

  const int lane = tid & 63;
  const int wave = tid >> 6;
  const int wr = wave >> 1;
  const int wc = wave & 1;

  const int arow = tid >> 3;
  const int ac8  = tid & 7;
  const float* xptr = X + (size_t)(bm * 128 + arow) * K_DIM + ac8 * 8;
  const unsigned int aswz = ((unsigned)arow & 7u) << 4;

  const int bc  = tid & 3;
  const int br0 = tid >> 2;
  const int* pwptr = PW + (size_t)(bn * 256 + br0) * (K_DIM / 4) + bc * 4;
  const int bwoff = (bc & 1) * 8 + (bc >> 1) * 2;

  f32x4 acc[4][8];
#pragma unroll
  for (int i = 0; i < 4; ++i)
#pragma unroll
    for (int j = 0; j < 8; ++j) acc[i][j] = (f32x4){0.f, 0.f, 0.f, 0.f};

  float4 av[4][2];
  int4 bv[4];
#pragma unroll
  for (int j = 0; j < 4; ++j) {
    av[j][0] = *(const float4*)(xptr + (size_t)(32 * j) * K_DIM);
    av[j][1] = *(const float4*)(xptr + (size_t)(32 * j) * K_DIM + 4);
  }
#pragma unroll
  for (int j = 0; j < 4; ++j)
    bv[j] = *(const int4*)(pwptr + (size_t)(64 * j) * (K_DIM / 4));

  for (int kt = 0; kt < 64; ++kt) {
    __syncthreads();
#pragma unroll
    for (int j = 0; j < 4; ++j) {
      uint4 wv;
      wv.x = bf16b(av[j][0].x) | (bf16b(av[j][0].y) << 16);
      wv.y = bf16b(av[j][0].z) | (bf16b(av[j][0].w) << 16);
      wv.z = bf16b(av[j][1].x) | (bf16b(av[j][1].y) << 16);
      wv.w = bf16b(av[j][1].z) | (bf16b(av[j][1].w) << 16);
      *(uint4*)((char*)Asf + (arow + 32 * j) * 128 + (((unsigned)ac8 * 16u) ^ aswz)) = wv;
    }
#pragma unroll
    for (int j = 0; j < 4; ++j) {
      const unsigned int ulo = ((unsigned)bv[j].x & 255u) | (((unsigned)bv[j].y & 255u) << 8);
      const unsigned int uhi = ((unsigned)bv[j].z & 255u) | (((unsigned)bv[j].w & 255u) << 8);
      unsigned char* dst = Bp + (br0 + 64 * j) * BSTRIDE + bwoff;
      *(unsigned short*)(dst)     = (unsigned short)ulo;
      *(unsigned short*)(dst + 4) = (unsigned short)uhi;
    }
    __syncthreads();

    if (kt + 1 < 64) {
#pragma unroll
      for (int j = 0; j < 4; ++j) {
        av[j][0] = *(const float4*)(xptr + (kt + 1) * 64 + (size_t)(32 * j) * K_DIM);
        av[j][1] = *(const float4*)(xptr + (kt + 1) * 64 + (size_t)(32 * j) * K_DIM + 4);
      }
#pragma unroll
      for (int j = 0; j < 4; ++j)
        bv[j] = *(const int4*)(pwptr + (kt + 1) * 16 + (size_t)(64 * j) * (K_DIM / 4));
    }

    const int bh = lane >> 4;
    const int bcol0 = wc * 128 + (lane & 15);
    unsigned int d[8];
#pragma unroll
    for (int n = 0; n < 8; ++n)
      d[n] = *(const unsigned int*)(Bp + (bcol0 + n * 16) * BSTRIDE + bh * 4);

    const unsigned int rswz = ((unsigned)lane & 7u) << 4;
#pragma unroll
    for (int kk = 0; kk < 2; ++kk) {
      bf16x8 af[4];
      const unsigned int coff = (((unsigned)(kk * 4 + (lane >> 4))) * 16u) ^ rswz;
#pragma unroll
      for (int m = 0; m < 4; ++m)
        af[m] = *(const bf16x8*)((const char*)Asf + (wr * 64 + m * 16 + (lane & 15)) * 128 + coff);
#pragma unroll
      for (int n = 0; n < 8; ++n) {
        const unsigned int w16 = kk ? (d[n] >> 16) : (d[n] & 0xFFFFu);
        const unsigned int u = w16 | (w16 << 14);
        union { uint4 s; bf16x8 v; } bfr;
        bfr.s.x = ((u << 14) & 0xC000C000u) + 0x40004000u;
        bfr.s.y = ((u << 10) & 0xC000C000u) + 0x40004000u;
        bfr.s.z = ((u << 6)  & 0xC000C000u) + 0x40004000u;
        bfr.s.w = ((u << 2)  & 0xC000C000u) + 0x40004000u;
#pragma unroll
        for (int m = 0; m < 4; ++m)
          acc[m][n] = __builtin_amdgcn_mfma_f32_16x16x32_bf16(af[m], bfr.v, acc[m][n], 0, 0, 0);
      }
    }
  }

  const int gc0 = bn * 256 + wc * 128 + (lane & 15);
  const int gr0 = bm * 128 + wr * 64 + ((lane >> 4) << 2);
  float sc[8];
#pragma unroll
  for (int n = 0; n < 8; ++n) sc[n] = -0.5f * SC[gc0 + n * 16];
#pragma unroll
  for (int m = 0; m < 4; ++m)
#pragma unroll
    for (int n = 0; n < 8; ++n)
#pragma unroll
      for (int r = 0; r < 4; ++r)
        OUT[(size_t)(gr0 + m * 16 + r) * N_DIM + gc0 + n * 16] = acc[m][n][r] * sc[n];
}

extern "C" void kernel_launch(void* const* d_in, const int* in_sizes, int n_in,
                              void* d_out, int out_size, void* d_ws, size_t ws_size,
                              hipStream_t stream) {
  const float* x  = (const float*)d_in[0];
  const int*   pw = (const int*)d_in[1];
  const float* sc = (const float*)d_in[2];
  float* out = (float*)d_out;
  (void)in_sizes; (void)n_in; (void)out_size;

  if (ws_size >= WS_NEED) {
    unsigned short* xbf = (unsigned short*)d_ws;
    unsigned char* bt = (unsigned char*)d_ws + XBF_BYTES;
    xcvt_kernel<<<dim3(XCVT_BLOCKS), dim3(256), 0, stream>>>(x, xbf);
    breorder_kernel<<<dim3(BRE_BLOCKS), dim3(256), 0, stream>>>(pw, bt);
    qlin_mm32_kernel<<<dim3(NWG), dim3(256), 0, stream>>>(xbf, bt, sc, out);
  } else {
    qlin_fused_kernel<<<dim3(NWG), dim3(256), 0, stream>>>(x, pw, sc, out);
  }
}